// Round 4
// baseline (173.277 us; speedup 1.0000x reference)
//
#include <hip/hip_runtime.h>

#define UNIT_NO 512
#define T_DIM 25
#define K_DIM 20
#define H_DIM 64
#define P_DIM 4096
#define F_DIM 10
#define BATCH 32
#define KTOT (K_DIM * F_DIM)   // 200
#define GT_LD 32               // Gt row stride (floats) — conflict-free (only 4 distinct b128 addrs/wave)
#define RED_LD 33              // reduction row stride (floats), breaks 128B-stride conflicts
#define KQ (KTOT / 4)          // 50 k-values per wave

// Kernel A: per-unit featurize for units [0, Ustar). Ft[u][f][b], batch contiguous.
__global__ __launch_bounds__(320) void featurize_kernel(
    const float* __restrict__ S, const float* __restrict__ Wf,
    const float* __restrict__ bf, float* __restrict__ Ft)
{
    const int u = blockIdx.x;
    __shared__ float Ws[T_DIM * F_DIM];   // [t][f]
    __shared__ float Ss[BATCH * T_DIM];   // [b][t]
    const int tid = threadIdx.x;
    for (int i = tid; i < T_DIM * F_DIM; i += 320)
        Ws[i] = Wf[u * (T_DIM * F_DIM) + i];
    for (int i = tid; i < BATCH * T_DIM; i += 320) {
        int b = i / T_DIM;
        int t = i - b * T_DIM;
        Ss[i] = S[b * (UNIT_NO * T_DIM) + u * T_DIM + t];
    }
    __syncthreads();
    const int f = tid >> 5;     // 0..9
    const int b = tid & 31;     // 0..31
    float acc = 0.f;
#pragma unroll
    for (int t = 0; t < T_DIM; ++t)
        acc = fmaf(Ss[b * T_DIM + t], Ws[t * F_DIM + f], acc);
    Ft[(u * F_DIM + f) * BATCH + b] = acc + bf[u * F_DIM + f];
}

#define FMA8(hh, wc)                                  \
    acc[hh][0] = fmaf(wc, g0.x, acc[hh][0]);          \
    acc[hh][1] = fmaf(wc, g0.y, acc[hh][1]);          \
    acc[hh][2] = fmaf(wc, g0.z, acc[hh][2]);          \
    acc[hh][3] = fmaf(wc, g0.w, acc[hh][3]);          \
    acc[hh][4] = fmaf(wc, g1.x, acc[hh][4]);          \
    acc[hh][5] = fmaf(wc, g1.y, acc[hh][5]);          \
    acc[hh][6] = fmaf(wc, g1.z, acc[hh][6]);          \
    acc[hh][7] = fmaf(wc, g1.w, acc[hh][7]);

// Kernel B: one block per pixel; 4 waves.
// Main loop: wave wv owns k in [50wv, 50wv+50) — W1 read exactly ONCE per block.
// Lane: h0 = (lane&15)*4 (4 h via dwordx4), oct = lane>>4 (batch octet).
// 5-deep register ring prefetch of W1 hides HBM/L3 latency.
// Cross-wave k-reduction through padded LDS (aliased over Gt), then epilogue.
__global__ __launch_bounds__(256, 4) void pixel_kernel(
    const float* __restrict__ Ft, const int* __restrict__ pix_units,
    const float* __restrict__ W1, const float* __restrict__ b1,
    const float* __restrict__ a, const float* __restrict__ Wo,
    const float* __restrict__ bo, float* __restrict__ out,
    const float* __restrict__ S, const float* __restrict__ Wf,
    const float* __restrict__ bf, int Ustar)
{
    const int p = blockIdx.x;
    const int tid = threadIdx.x;
    const int lane = tid & 63;
    const int wv = tid >> 6;

    // Aliased shared memory: Gt (200x32 fl = 25.6 KB) for the main loop,
    // red (256x33 fl = 33.8 KB) for the cross-wave reduction (after barrier).
    __shared__ __align__(16) char smem_raw[4 * H_DIM * RED_LD * sizeof(float)];
    float (*Gt)[GT_LD]  = (float (*)[GT_LD])smem_raw;
    float (*red)[RED_LD] = (float (*)[RED_LD])smem_raw;
    __shared__ int us[K_DIM];

    if (tid < K_DIM) us[tid] = pix_units[p * K_DIM + tid];
    __syncthreads();

    // Stage gathered features as float4: Gt[j*10+f][b] = F[us[j]][f][b]
    for (int o4 = tid; o4 < KTOT * (BATCH / 4); o4 += 256) {  // 1600 float4s
        const int r  = o4 >> 3;       // row 0..199
        const int b4 = o4 & 7;        // float4 slot in row
        const int j  = r / F_DIM;
        const int f  = r - j * F_DIM;
        const int u  = us[j];
        float4 v;
        if (u < Ustar) {
            v = *(const float4*)(Ft + ((u * F_DIM + f) << 5) + (b4 << 2));
        } else {
            float vv[4];
#pragma unroll
            for (int q = 0; q < 4; ++q) {
                const int b = (b4 << 2) + q;
                float acc = bf[u * F_DIM + f];
                const float* __restrict__ sp = S + b * (UNIT_NO * T_DIM) + u * T_DIM;
                const float* __restrict__ wp = Wf + u * (T_DIM * F_DIM) + f;
#pragma unroll
                for (int t = 0; t < T_DIM; ++t)
                    vv[q] = acc = fmaf(sp[t], wp[t * F_DIM], acc);
            }
            v = make_float4(vv[0], vv[1], vv[2], vv[3]);
        }
        *(float4*)(&Gt[r][b4 << 2]) = v;
    }
    __syncthreads();

    const int oct = lane >> 4;          // batch octet 0..3
    const int h0  = (lane & 15) << 2;   // h base 0..60
    const int kbase = wv * KQ;          // this wave's k range

    const float* __restrict__ w1p =
        W1 + (size_t)p * (KTOT * H_DIM) + (size_t)kbase * H_DIM + h0;
    const float* __restrict__ gkp = &Gt[kbase][oct * 8];

    float acc[4][8];
#pragma unroll
    for (int hh = 0; hh < 4; ++hh)
#pragma unroll
        for (int i = 0; i < 8; ++i) acc[hh][i] = 0.f;

    // Register ring: W1 rows prefetched 5 iterations ahead.
    float4 w[5];
#pragma unroll
    for (int i = 0; i < 5; ++i)
        w[i] = *(const float4*)(w1p + i * H_DIM);

#pragma unroll 5
    for (int kg = 0; kg < KQ; ++kg) {
        const float4 wc = w[kg % 5];
        int kn = kg + 5;
        if (kn >= KQ) kn = KQ - 1;      // harmless redundant reload in the tail
        w[kg % 5] = *(const float4*)(w1p + kn * H_DIM);
        const float* g = gkp + kg * GT_LD;
        const float4 g0 = *(const float4*)(g);       // broadcast, conflict-free
        const float4 g1 = *(const float4*)(g + 4);
        FMA8(0, wc.x)
        FMA8(1, wc.y)
        FMA8(2, wc.z)
        FMA8(3, wc.w)
    }

    // Cross-wave reduction: wave wv's partials -> red[wv*64 + h][b]
    __syncthreads();   // everyone done reading Gt (red aliases it)
#pragma unroll
    for (int hh = 0; hh < 4; ++hh)
#pragma unroll
        for (int j = 0; j < 8; ++j)
            red[wv * H_DIM + h0 + hh][oct * 8 + j] = acc[hh][j];
    __syncthreads();

    // Epilogue: wave wv owns batch octet wv; lane covers h0 (16 groups) x 2 batches.
    const int bp = (lane >> 4) << 1;    // batch pair within octet: 0,2,4,6
    const float4 b1v = *(const float4*)(b1 + p * H_DIM + h0);
    const float4 wov = *(const float4*)(Wo + p * H_DIM + h0);
    const float b1a[4] = {b1v.x, b1v.y, b1v.z, b1v.w};
    const float woa[4] = {wov.x, wov.y, wov.z, wov.w};
    const float av = a[p];
    float s[2];
#pragma unroll
    for (int bb = 0; bb < 2; ++bb) {
        const int b = (wv << 3) + bp + bb;  // global batch
        float sv = 0.f;
#pragma unroll
        for (int i = 0; i < 4; ++i) {
            float v = red[0 * H_DIM + h0 + i][b] + red[1 * H_DIM + h0 + i][b]
                    + red[2 * H_DIM + h0 + i][b] + red[3 * H_DIM + h0 + i][b];
            v += b1a[i];
            v = (v >= 0.f) ? v : av * v;
            sv = fmaf(v, woa[i], sv);
        }
        s[bb] = sv;
    }
    // Sum over the 16 h-groups (lane bits 0..3)
#pragma unroll
    for (int off = 1; off < 16; off <<= 1) {
        s[0] += __shfl_xor(s[0], off);
        s[1] += __shfl_xor(s[1], off);
    }
    if ((lane & 15) == 0) {
        const float bov = bo[p];
        const int b = (wv << 3) + bp;
        out[(size_t)b * P_DIM + p]       = s[0] + bov;
        out[(size_t)(b + 1) * P_DIM + p] = s[1] + bov;
    }
}

extern "C" void kernel_launch(void* const* d_in, const int* in_sizes, int n_in,
                              void* d_out, int out_size, void* d_ws, size_t ws_size,
                              hipStream_t stream) {
    const float* S         = (const float*)d_in[0];
    const int*   pix_units = (const int*)d_in[1];
    const float* Wf        = (const float*)d_in[2];
    const float* bf        = (const float*)d_in[3];
    const float* W1        = (const float*)d_in[4];
    const float* b1        = (const float*)d_in[5];
    const float* a         = (const float*)d_in[6];
    const float* Wo        = (const float*)d_in[7];
    const float* bo        = (const float*)d_in[8];
    float* out = (float*)d_out;
    float* Ft  = (float*)d_ws;

    // Units whose [10][32] fp32 tile fits in ws_size; rest recomputed in-block.
    int Ustar = (int)(ws_size / (size_t)(F_DIM * BATCH * sizeof(float)));
    if (Ustar > UNIT_NO) Ustar = UNIT_NO;

    if (Ustar > 0)
        featurize_kernel<<<Ustar, 320, 0, stream>>>(S, Wf, bf, Ft);
    pixel_kernel<<<P_DIM, 256, 0, stream>>>(Ft, pix_units, W1, b1, a, Wo, bo, out,
                                            S, Wf, bf, Ustar);
}

// Round 5
// 120.397 us; speedup vs baseline: 1.4392x; 1.4392x over previous
//
#include <hip/hip_runtime.h>

#define UNIT_NO 512
#define T_DIM 25
#define K_DIM 20
#define H_DIM 64
#define P_DIM 4096
#define F_DIM 10
#define BATCH 32
#define KTOT (K_DIM * F_DIM)   // 200
#define GT_LD 32               // R2-measured conflict-free; 25.6 KB -> 6 blocks/CU

// Kernel A: per-unit featurize for units [0, Ustar). Ft[u][f][b], batch contiguous.
__global__ __launch_bounds__(320) void featurize_kernel(
    const float* __restrict__ S, const float* __restrict__ Wf,
    const float* __restrict__ bf, float* __restrict__ Ft)
{
    const int u = blockIdx.x;
    __shared__ float Ws[T_DIM * F_DIM];   // [t][f]
    __shared__ float Ss[BATCH * T_DIM];   // [b][t]
    const int tid = threadIdx.x;
    for (int i = tid; i < T_DIM * F_DIM; i += 320)
        Ws[i] = Wf[u * (T_DIM * F_DIM) + i];
    for (int i = tid; i < BATCH * T_DIM; i += 320) {
        int b = i / T_DIM;
        int t = i - b * T_DIM;
        Ss[i] = S[b * (UNIT_NO * T_DIM) + u * T_DIM + t];
    }
    __syncthreads();
    const int f = tid >> 5;     // 0..9
    const int b = tid & 31;     // 0..31
    float acc = 0.f;
#pragma unroll
    for (int t = 0; t < T_DIM; ++t)
        acc = fmaf(Ss[b * T_DIM + t], Ws[t * F_DIM + f], acc);
    Ft[(u * F_DIM + f) * BATCH + b] = acc + bf[u * F_DIM + f];
}

#define FMA8(hh, wc)                                  \
    acc[hh][0] = fmaf(wc, g0.x, acc[hh][0]);          \
    acc[hh][1] = fmaf(wc, g0.y, acc[hh][1]);          \
    acc[hh][2] = fmaf(wc, g0.z, acc[hh][2]);          \
    acc[hh][3] = fmaf(wc, g0.w, acc[hh][3]);          \
    acc[hh][4] = fmaf(wc, g1.x, acc[hh][4]);          \
    acc[hh][5] = fmaf(wc, g1.y, acc[hh][5]);          \
    acc[hh][6] = fmaf(wc, g1.z, acc[hh][6]);          \
    acc[hh][7] = fmaf(wc, g1.w, acc[hh][7]);

// Kernel B: one block per pixel; 4 waves; wave wv owns batches [8wv, 8wv+8).
// Lane split: h0 = (lane&15)*4 (4 h via dwordx4), kq = lane>>4 (k phase mod 4).
// Per load instruction the wave covers 4 consecutive W1 rows x 64 h = 1KB contiguous.
__global__ __launch_bounds__(256, 6) void pixel_kernel(
    const float* __restrict__ Ft, const int* __restrict__ pix_units,
    const float* __restrict__ W1, const float* __restrict__ b1,
    const float* __restrict__ a, const float* __restrict__ Wo,
    const float* __restrict__ bo, float* __restrict__ out,
    const float* __restrict__ S, const float* __restrict__ Wf,
    const float* __restrict__ bf, int Ustar)
{
    const int p = blockIdx.x;
    const int tid = threadIdx.x;
    const int lane = tid & 63;
    const int wv = tid >> 6;

    __shared__ float Gt[KTOT][GT_LD];   // 200 x 32 floats = 25.6 KB
    __shared__ int us[K_DIM];

    if (tid < K_DIM) us[tid] = pix_units[p * K_DIM + tid];
    __syncthreads();

    // Stage gathered features as float4: Gt[j*10+f][b] = F[us[j]][f][b]
    for (int o4 = tid; o4 < KTOT * (BATCH / 4); o4 += 256) {  // 1600 float4s
        const int r  = o4 >> 3;       // row 0..199
        const int b4 = o4 & 7;        // float4 slot in row
        const int j  = r / F_DIM;
        const int f  = r - j * F_DIM;
        const int u  = us[j];
        float4 v;
        if (u < Ustar) {
            v = *(const float4*)(Ft + ((u * F_DIM + f) << 5) + (b4 << 2));
        } else {
            float vv[4];
#pragma unroll
            for (int q = 0; q < 4; ++q) {
                const int b = (b4 << 2) + q;
                float acc = bf[u * F_DIM + f];
                const float* __restrict__ sp = S + b * (UNIT_NO * T_DIM) + u * T_DIM;
                const float* __restrict__ wp = Wf + u * (T_DIM * F_DIM) + f;
#pragma unroll
                for (int t = 0; t < T_DIM; ++t)
                    vv[q] = acc = fmaf(sp[t], wp[t * F_DIM], acc);
            }
            v = make_float4(vv[0], vv[1], vv[2], vv[3]);
        }
        *(float4*)(&Gt[r][b4 << 2]) = v;
    }
    __syncthreads();

    const int kq = lane >> 4;          // k phase 0..3
    const int h0 = (lane & 15) << 2;   // h base 0..60

    const float* __restrict__ w1p =
        W1 + (size_t)p * (KTOT * H_DIM) + kq * H_DIM + h0;
    const float* __restrict__ gkp = &Gt[kq][wv * 8];

    float acc[4][8];
#pragma unroll
    for (int hh = 0; hh < 4; ++hh)
#pragma unroll
        for (int i = 0; i < 8; ++i) acc[hh][i] = 0.f;

    // k = 4*kg + kq; per iter: 1 dwordx4 (1KB/wave coalesced), 2 broadcast b128, 32 FMA
#pragma unroll 5
    for (int kg = 0; kg < KTOT / 4; ++kg) {
        const float4 w  = *(const float4*)(w1p + kg * (4 * H_DIM));
        const float* g  = gkp + kg * (4 * GT_LD);
        const float4 g0 = *(const float4*)(g);       // broadcast
        const float4 g1 = *(const float4*)(g + 4);   // broadcast
        FMA8(0, w.x)
        FMA8(1, w.y)
        FMA8(2, w.z)
        FMA8(3, w.w)
    }

    // Combine the 4 k-phases: lanes l, l^16, l^32, l^48 hold disjoint k-subsets.
#pragma unroll
    for (int hh = 0; hh < 4; ++hh)
#pragma unroll
        for (int i = 0; i < 8; ++i) {
            float v = acc[hh][i];
            v += __shfl_xor(v, 16);
            v += __shfl_xor(v, 32);
            acc[hh][i] = v;
        }

    // Epilogue: bias + PReLU + Wo dot over this lane's 4 h's
    const float4 b1v = *(const float4*)(b1 + p * H_DIM + h0);
    const float4 wov = *(const float4*)(Wo + p * H_DIM + h0);
    const float av = a[p];
    float s[8];
#pragma unroll
    for (int i = 0; i < 8; ++i) {
        float v0 = acc[0][i] + b1v.x; v0 = (v0 >= 0.f) ? v0 : av * v0;
        float v1 = acc[1][i] + b1v.y; v1 = (v1 >= 0.f) ? v1 : av * v1;
        float v2 = acc[2][i] + b1v.z; v2 = (v2 >= 0.f) ? v2 : av * v2;
        float v3 = acc[3][i] + b1v.w; v3 = (v3 >= 0.f) ? v3 : av * v3;
        s[i] = fmaf(v0, wov.x, fmaf(v1, wov.y, fmaf(v2, wov.z, v3 * wov.w)));
    }
    // Sum over the 16 h-groups
#pragma unroll
    for (int off = 1; off < 16; off <<= 1)
#pragma unroll
        for (int i = 0; i < 8; ++i) s[i] += __shfl_xor(s[i], off);

    if (lane == 0) {
        const float bov = bo[p];
#pragma unroll
        for (int i = 0; i < 8; ++i)
            out[(size_t)(wv * 8 + i) * P_DIM + p] = s[i] + bov;
    }
}

extern "C" void kernel_launch(void* const* d_in, const int* in_sizes, int n_in,
                              void* d_out, int out_size, void* d_ws, size_t ws_size,
                              hipStream_t stream) {
    const float* S         = (const float*)d_in[0];
    const int*   pix_units = (const int*)d_in[1];
    const float* Wf        = (const float*)d_in[2];
    const float* bf        = (const float*)d_in[3];
    const float* W1        = (const float*)d_in[4];
    const float* b1        = (const float*)d_in[5];
    const float* a         = (const float*)d_in[6];
    const float* Wo        = (const float*)d_in[7];
    const float* bo        = (const float*)d_in[8];
    float* out = (float*)d_out;
    float* Ft  = (float*)d_ws;

    // Units whose [10][32] fp32 tile fits in ws_size; rest recomputed in-block.
    int Ustar = (int)(ws_size / (size_t)(F_DIM * BATCH * sizeof(float)));
    if (Ustar > UNIT_NO) Ustar = UNIT_NO;

    if (Ustar > 0)
        featurize_kernel<<<Ustar, 320, 0, stream>>>(S, Wf, bf, Ft);
    pixel_kernel<<<P_DIM, 256, 0, stream>>>(Ft, pix_units, W1, b1, a, Wo, bo, out,
                                            S, Wf, bf, Ustar);
}

// Round 6
// 73.856 us; speedup vs baseline: 2.3461x; 1.6302x over previous
//
#include <hip/hip_runtime.h>

#define UNIT_NO 512
#define T_DIM 25
#define K_DIM 20
#define H_DIM 64
#define P_DIM 4096
#define F_DIM 10
#define BATCH 32
#define KTOT (K_DIM * F_DIM)   // 200
#define GT_LD 32               // measured conflict-free (R5); 25.6 KB

// Kernel A: per-unit featurize for units [0, Ustar). Ft[u][f][b], batch contiguous.
__global__ __launch_bounds__(320) void featurize_kernel(
    const float* __restrict__ S, const float* __restrict__ Wf,
    const float* __restrict__ bf, float* __restrict__ Ft)
{
    const int u = blockIdx.x;
    __shared__ float Ws[T_DIM * F_DIM];   // [t][f]
    __shared__ float Ss[BATCH * T_DIM];   // [b][t]
    const int tid = threadIdx.x;
    for (int i = tid; i < T_DIM * F_DIM; i += 320)
        Ws[i] = Wf[u * (T_DIM * F_DIM) + i];
    for (int i = tid; i < BATCH * T_DIM; i += 320) {
        int b = i / T_DIM;
        int t = i - b * T_DIM;
        Ss[i] = S[b * (UNIT_NO * T_DIM) + u * T_DIM + t];
    }
    __syncthreads();
    const int f = tid >> 5;     // 0..9
    const int b = tid & 31;     // 0..31
    float acc = 0.f;
#pragma unroll
    for (int t = 0; t < T_DIM; ++t)
        acc = fmaf(Ss[b * T_DIM + t], Ws[t * F_DIM + f], acc);
    Ft[(u * F_DIM + f) * BATCH + b] = acc + bf[u * F_DIM + f];
}

#define FMA8(hh, wc)                                  \
    acc[hh][0] = fmaf(wc, g0.x, acc[hh][0]);          \
    acc[hh][1] = fmaf(wc, g0.y, acc[hh][1]);          \
    acc[hh][2] = fmaf(wc, g0.z, acc[hh][2]);          \
    acc[hh][3] = fmaf(wc, g0.w, acc[hh][3]);          \
    acc[hh][4] = fmaf(wc, g1.x, acc[hh][4]);          \
    acc[hh][5] = fmaf(wc, g1.y, acc[hh][5]);          \
    acc[hh][6] = fmaf(wc, g1.z, acc[hh][6]);          \
    acc[hh][7] = fmaf(wc, g1.w, acc[hh][7]);

// Kernel B: one block per pixel; 4 waves; wave wv owns batches [8wv, 8wv+8).
// Lane split: h0 = (lane&15)*4 (4 h via dwordx4), kq = lane>>4 (k phase mod 4).
// Per load instruction the wave covers 4 consecutive W1 rows x 64 h = 1KB contiguous.
// MUST run at 4 waves/SIMD (VGPR<=128): 6 waves/SIMD caps VGPR at 64 and spills
// the accumulators to scratch (R5: WRITE_SIZE 137MB, 180us — 3x regression).
__global__ __launch_bounds__(256, 4) void pixel_kernel(
    const float* __restrict__ Ft, const int* __restrict__ pix_units,
    const float* __restrict__ W1, const float* __restrict__ b1,
    const float* __restrict__ a, const float* __restrict__ Wo,
    const float* __restrict__ bo, float* __restrict__ out,
    const float* __restrict__ S, const float* __restrict__ Wf,
    const float* __restrict__ bf, int Ustar)
{
    const int p = blockIdx.x;
    const int tid = threadIdx.x;
    const int lane = tid & 63;
    const int wv = tid >> 6;

    __shared__ float Gt[KTOT][GT_LD];   // 200 x 32 floats = 25.6 KB
    __shared__ int us[K_DIM];

    if (tid < K_DIM) us[tid] = pix_units[p * K_DIM + tid];
    __syncthreads();

    // Stage gathered features as float4: Gt[j*10+f][b] = F[us[j]][f][b]
    for (int o4 = tid; o4 < KTOT * (BATCH / 4); o4 += 256) {  // 1600 float4s
        const int r  = o4 >> 3;       // row 0..199
        const int b4 = o4 & 7;        // float4 slot in row
        const int j  = r / F_DIM;
        const int f  = r - j * F_DIM;
        const int u  = us[j];
        float4 v;
        if (u < Ustar) {
            v = *(const float4*)(Ft + ((u * F_DIM + f) << 5) + (b4 << 2));
        } else {
            float vv[4];
#pragma unroll
            for (int q = 0; q < 4; ++q) {
                const int b = (b4 << 2) + q;
                float acc = bf[u * F_DIM + f];
                const float* __restrict__ sp = S + b * (UNIT_NO * T_DIM) + u * T_DIM;
                const float* __restrict__ wp = Wf + u * (T_DIM * F_DIM) + f;
#pragma unroll
                for (int t = 0; t < T_DIM; ++t)
                    vv[q] = acc = fmaf(sp[t], wp[t * F_DIM], acc);
            }
            v = make_float4(vv[0], vv[1], vv[2], vv[3]);
        }
        *(float4*)(&Gt[r][b4 << 2]) = v;
    }
    __syncthreads();

    const int kq = lane >> 4;          // k phase 0..3
    const int h0 = (lane & 15) << 2;   // h base 0..60

    const float* __restrict__ w1p =
        W1 + (size_t)p * (KTOT * H_DIM) + kq * H_DIM + h0;
    const float* __restrict__ gkp = &Gt[kq][wv * 8];

    float acc[4][8];
#pragma unroll
    for (int hh = 0; hh < 4; ++hh)
#pragma unroll
        for (int i = 0; i < 8; ++i) acc[hh][i] = 0.f;

    // k = 4*kg + kq; per iter: 1 dwordx4 (1KB/wave coalesced), 2 broadcast b128, 32 FMA
    // unroll 10: ~10 loads (2.5KB) in flight per wave for latency hiding.
#pragma unroll 10
    for (int kg = 0; kg < KTOT / 4; ++kg) {
        const float4 w  = *(const float4*)(w1p + kg * (4 * H_DIM));
        const float* g  = gkp + kg * (4 * GT_LD);
        const float4 g0 = *(const float4*)(g);       // broadcast
        const float4 g1 = *(const float4*)(g + 4);   // broadcast
        FMA8(0, w.x)
        FMA8(1, w.y)
        FMA8(2, w.z)
        FMA8(3, w.w)
    }

    // Combine the 4 k-phases: lanes l, l^16, l^32, l^48 hold disjoint k-subsets.
#pragma unroll
    for (int hh = 0; hh < 4; ++hh)
#pragma unroll
        for (int i = 0; i < 8; ++i) {
            float v = acc[hh][i];
            v += __shfl_xor(v, 16);
            v += __shfl_xor(v, 32);
            acc[hh][i] = v;
        }

    // Epilogue: bias + PReLU + Wo dot over this lane's 4 h's
    const float4 b1v = *(const float4*)(b1 + p * H_DIM + h0);
    const float4 wov = *(const float4*)(Wo + p * H_DIM + h0);
    const float av = a[p];
    float s[8];
#pragma unroll
    for (int i = 0; i < 8; ++i) {
        float v0 = acc[0][i] + b1v.x; v0 = (v0 >= 0.f) ? v0 : av * v0;
        float v1 = acc[1][i] + b1v.y; v1 = (v1 >= 0.f) ? v1 : av * v1;
        float v2 = acc[2][i] + b1v.z; v2 = (v2 >= 0.f) ? v2 : av * v2;
        float v3 = acc[3][i] + b1v.w; v3 = (v3 >= 0.f) ? v3 : av * v3;
        s[i] = fmaf(v0, wov.x, fmaf(v1, wov.y, fmaf(v2, wov.z, v3 * wov.w)));
    }
    // Sum over the 16 h-groups
#pragma unroll
    for (int off = 1; off < 16; off <<= 1)
#pragma unroll
        for (int i = 0; i < 8; ++i) s[i] += __shfl_xor(s[i], off);

    if (lane == 0) {
        const float bov = bo[p];
#pragma unroll
        for (int i = 0; i < 8; ++i)
            out[(size_t)(wv * 8 + i) * P_DIM + p] = s[i] + bov;
    }
}

extern "C" void kernel_launch(void* const* d_in, const int* in_sizes, int n_in,
                              void* d_out, int out_size, void* d_ws, size_t ws_size,
                              hipStream_t stream) {
    const float* S         = (const float*)d_in[0];
    const int*   pix_units = (const int*)d_in[1];
    const float* Wf        = (const float*)d_in[2];
    const float* bf        = (const float*)d_in[3];
    const float* W1        = (const float*)d_in[4];
    const float* b1        = (const float*)d_in[5];
    const float* a         = (const float*)d_in[6];
    const float* Wo        = (const float*)d_in[7];
    const float* bo        = (const float*)d_in[8];
    float* out = (float*)d_out;
    float* Ft  = (float*)d_ws;

    // Units whose [10][32] fp32 tile fits in ws_size; rest recomputed in-block.
    int Ustar = (int)(ws_size / (size_t)(F_DIM * BATCH * sizeof(float)));
    if (Ustar > UNIT_NO) Ustar = UNIT_NO;

    if (Ustar > 0)
        featurize_kernel<<<Ustar, 320, 0, stream>>>(S, Wf, bf, Ft);
    pixel_kernel<<<P_DIM, 256, 0, stream>>>(Ft, pix_units, W1, b1, a, Wo, bo, out,
                                            S, Wf, bf, Ustar);
}